// Round 1
// baseline (545.979 us; speedup 1.0000x reference)
//
#include <hip/hip_runtime.h>
#include <hip/hip_bf16.h>
#include <stdint.h>

#define NROW 8192
#define DIM  256
#define TILE 128
#define BK   64

typedef unsigned short u16;
typedef __attribute__((ext_vector_type(8))) short short8;
typedef __attribute__((ext_vector_type(4))) float f32x4;

__device__ __forceinline__ void load_lds16(const void* g, void* l) {
    __builtin_amdgcn_global_load_lds(
        (const __attribute__((address_space(1))) void*)g,
        (__attribute__((address_space(3))) void*)l,
        16, 0, 0);
}

// Kernel 1: fp32 -> bf16 (RNE) + per-row sum of squares (x2)
__global__ __launch_bounds__(256) void prep_kernel(const float* __restrict__ emb,
                                                   u16* __restrict__ ebf,
                                                   float* __restrict__ x2) {
    const int row = blockIdx.x;
    const int tid = threadIdx.x;
    float v = emb[(size_t)row * DIM + tid];
    uint32_t bits = __float_as_uint(v);
    uint32_t r = (bits + 0x7FFFu + ((bits >> 16) & 1u)) >> 16;  // round-to-nearest-even
    ebf[(size_t)row * DIM + tid] = (u16)r;
    float s = v * v;
#pragma unroll
    for (int off = 32; off > 0; off >>= 1) s += __shfl_down(s, off, 64);
    __shared__ float ws4[4];
    if ((tid & 63) == 0) ws4[tid >> 6] = s;
    __syncthreads();
    if (tid == 0) x2[row] = ws4[0] + ws4[1] + ws4[2] + ws4[3];
}

// Kernel 2: tiled E*E^T (bf16 MFMA) with fused Poincare epilogue.
__global__ __launch_bounds__(256, 2) void poincare_kernel(const u16* __restrict__ ebf,
                                                          const float* __restrict__ x2,
                                                          float* __restrict__ out) {
    // LDS tiles, [128 rows][64 k-elems] bf16, XOR-swizzled in 16B chunks:
    // slot (row, s) holds global k-chunk (s ^ (row & 7)).
    __shared__ __align__(16) u16 Asm[TILE * BK];
    __shared__ __align__(16) u16 Bsm[TILE * BK];

    const int tid  = threadIdx.x;
    const int wave = tid >> 6;
    const int lane = tid & 63;

    const int brow = blockIdx.x * TILE;
    const int bcol = blockIdx.y * TILE;

    const int wm = (wave & 1) * 64;   // wave row offset inside tile
    const int wn = (wave >> 1) * 64;  // wave col offset inside tile

    f32x4 acc[4][4];
#pragma unroll
    for (int m = 0; m < 4; ++m)
#pragma unroll
        for (int n = 0; n < 4; ++n) acc[m][n] = (f32x4){0.f, 0.f, 0.f, 0.f};

    // staging: lane -> slot (srow = lane>>3, schunk = lane&7); gptr fetches the
    // swizzled logical chunk so the LDS write stays base + lane*16.
    const int srow = lane >> 3;
    const int sc   = (((lane & 7) ^ srow) * 8);  // element offset within row

    const int lcol  = lane & 15;
    const int quad  = lane >> 4;
    const int chbase = quad ^ (lane & 7);        // read-side swizzled chunk, ks=0

    for (int k0 = 0; k0 < DIM; k0 += BK) {
#pragma unroll
        for (int t = 0; t < 4; ++t) {
            const int rr = wave * 32 + t * 8;  // wave-uniform group base row
            const u16* gA = ebf + (size_t)(brow + rr + srow) * DIM + k0 + sc;
            const u16* gB = ebf + (size_t)(bcol + rr + srow) * DIM + k0 + sc;
            load_lds16(gA, &Asm[rr * BK]);
            load_lds16(gB, &Bsm[rr * BK]);
        }
        __syncthreads();

#pragma unroll
        for (int ks = 0; ks < 2; ++ks) {
            const int cc = chbase ^ (ks << 2);
            short8 af[4], bfr[4];
#pragma unroll
            for (int m = 0; m < 4; ++m) {
                const int row = wm + m * 16 + lcol;
                af[m] = *(const short8*)&Asm[row * BK + cc * 8];
            }
#pragma unroll
            for (int n = 0; n < 4; ++n) {
                const int row = wn + n * 16 + lcol;
                bfr[n] = *(const short8*)&Bsm[row * BK + cc * 8];
            }
#pragma unroll
            for (int m = 0; m < 4; ++m)
#pragma unroll
                for (int n = 0; n < 4; ++n)
                    acc[m][n] = __builtin_amdgcn_mfma_f32_16x16x32_bf16(
                        af[m], bfr[n], acc[m][n], 0, 0, 0);
        }
        __syncthreads();
    }

    // Epilogue. C/D layout: col = lane&15, row = quad*4 + reg.
    float xj2v[4];
#pragma unroll
    for (int n = 0; n < 4; ++n) xj2v[n] = x2[bcol + wn + n * 16 + lcol];

    float* __restrict__ probs = out;
    float* __restrict__ dists = out + (size_t)NROW * NROW;

#pragma unroll
    for (int m = 0; m < 4; ++m) {
#pragma unroll
        for (int r = 0; r < 4; ++r) {
            const int grow = brow + wm + m * 16 + quad * 4 + r;
            const float xi2 = x2[grow];
            const float Bv = 1.f - xi2;
            const size_t rowoff = (size_t)grow * NROW;
#pragma unroll
            for (int n = 0; n < 4; ++n) {
                const int gcol = bcol + wn + n * 16 + lcol;
                const float dot = acc[m][n][r];
                const float xj2 = xj2v[n];
                const float Av = 1.f - 2.f * dot + xj2;
                const float Dv = 1.f - 2.f * dot + xi2 * xj2;
                float num2 = Av * Av * xi2 - 2.f * Av * Bv * dot + Bv * Bv * xj2;
                num2 = fmaxf(num2, 0.f);
                const float den = fmaxf(fabsf(Dv), 1e-15f);
                float t = __builtin_amdgcn_sqrtf(num2) * __builtin_amdgcn_rcpf(den);
                t = fminf(t, 1.f - 1e-7f);
                float dist = __logf((1.f + t) * __builtin_amdgcn_rcpf(1.f - t));
                float prob = 0.5f * (1.f - t);
                if (grow == gcol) { dist = 0.f; prob = 0.f; }
                probs[rowoff + gcol] = prob;
                dists[rowoff + gcol] = dist;
            }
        }
    }
}

extern "C" void kernel_launch(void* const* d_in, const int* in_sizes, int n_in,
                              void* d_out, int out_size, void* d_ws, size_t ws_size,
                              hipStream_t stream) {
    (void)in_sizes; (void)n_in; (void)out_size; (void)ws_size;
    const float* emb = (const float*)d_in[0];
    float* out = (float*)d_out;
    u16*   ebf = (u16*)d_ws;
    float* x2  = (float*)((char*)d_ws + (size_t)NROW * DIM * sizeof(u16));

    prep_kernel<<<NROW, 256, 0, stream>>>(emb, ebf, x2);
    dim3 grid(NROW / TILE, NROW / TILE);
    poincare_kernel<<<grid, 256, 0, stream>>>(ebf, x2, out);
}